// Round 7
// baseline (810.401 us; speedup 1.0000x reference)
//
#include <hip/hip_runtime.h>

#define NN 100000
#define EE 1600000
#define DD 128
#define LL 3

typedef float f32x4 __attribute__((ext_vector_type(4)));
typedef _Float16 f16x8 __attribute__((ext_vector_type(8)));
typedef _Float16 f16x2 __attribute__((ext_vector_type(2)));
typedef unsigned short u16;
typedef unsigned int u32;
typedef u16 u16x8 __attribute__((ext_vector_type(8)));

// CSR-build geometry: buckets of 256 nodes, chunks of 16384 edges
#define NBUCK ((NN + 255) / 256)          // 391
#define CHUNK 16384
#define NCHUNK ((EE + CHUNK - 1) / CHUNK) // 98
#define PADMAX 1024                        // 256 nodes * 3 max pad, rounded up

__device__ __forceinline__ u16 f2h_bits(float f) {
    _Float16 h = (_Float16)f;
    return __builtin_bit_cast(u16, h);
}
__device__ __forceinline__ f16x2 bc16x2(u32 v) {
    return __builtin_bit_cast(f16x2, v);
}
__device__ __forceinline__ u32 f22h(float x, float y) {
    return (u32)f2h_bits(x) | ((u32)f2h_bits(y) << 16);
}

// ---------------- CSR build: bucketed counting sort by dst ----------------

__global__ __launch_bounds__(1024) void csr_hist(const int* __restrict__ dst,
                                                 int* __restrict__ hist_g) {
    __shared__ int h[NBUCK];
    int t = threadIdx.x, c = blockIdx.x;
    for (int i = t; i < NBUCK; i += 1024) h[i] = 0;
    __syncthreads();
    int base = c * CHUNK;
    #pragma unroll
    for (int i = 0; i < CHUNK / 1024; ++i) {
        int e = base + t + i * 1024;
        if (e < EE) atomicAdd(&h[dst[e] >> 8], 1);
    }
    __syncthreads();
    for (int i = t; i < NBUCK; i += 1024) hist_g[i * NCHUNK + c] = h[i];
}

__global__ __launch_bounds__(512) void csr_scan(int* __restrict__ hist_g,
                                                int* __restrict__ bbase) {
    __shared__ int tot[512];
    int t = threadIdx.x;
    int sum = 0;
    if (t < NBUCK) {
        int* p = hist_g + t * NCHUNK;
        for (int c = 0; c < NCHUNK; ++c) { int v = p[c]; p[c] = sum; sum += v; }
    }
    tot[t] = sum; __syncthreads();
    for (int off = 1; off < 512; off <<= 1) {
        int u = (t >= off) ? tot[t - off] : 0;
        __syncthreads();
        tot[t] += u;
        __syncthreads();
    }
    int base = tot[t] - sum;   // exclusive
    if (t < NBUCK) {
        bbase[t] = base;
        int* p = hist_g + t * NCHUNK;
        for (int c = 0; c < NCHUNK; ++c) p[c] += base;
    }
    if (t == 0) bbase[NBUCK] = EE;
}

__global__ __launch_bounds__(1024) void csr_scatter(const int* __restrict__ src,
                                                    const int* __restrict__ dst,
                                                    const int* __restrict__ hist_g,
                                                    u32* __restrict__ rec) {
    __shared__ int cur[NBUCK];
    int t = threadIdx.x, c = blockIdx.x;
    for (int i = t; i < NBUCK; i += 1024) cur[i] = hist_g[i * NCHUNK + c];
    __syncthreads();
    int base = c * CHUNK;
    #pragma unroll
    for (int i = 0; i < CHUNK / 1024; ++i) {
        int e = base + t + i * 1024;
        if (e < EE) {
            int d = dst[e];
            int slot = atomicAdd(&cur[d >> 8], 1);
            rec[slot] = (u32)src[e] | ((u32)(d & 255) << 17);
        }
    }
}

// one block per bucket: padded (multiple-of-4) per-node segments, pad -> node NN
__global__ __launch_bounds__(256) void csr_finalize(const u32* __restrict__ rec,
                                                    const int* __restrict__ bbase,
                                                    int* __restrict__ rbeg,
                                                    int* __restrict__ rpend,
                                                    int* __restrict__ col) {
    __shared__ int cur[256];
    __shared__ int sc[256];
    int b = blockIdx.x, t = threadIdx.x;
    int base = bbase[b], tot = bbase[b + 1] - base;
    int pbase = base + b * PADMAX;
    sc[t] = 0; __syncthreads();
    for (int r = t; r < tot; r += 256) atomicAdd(&sc[rec[base + r] >> 17], 1);
    __syncthreads();
    int cnt = sc[t];
    int pcnt = (cnt + 3) & ~3;
    // inclusive scan of pcnt
    sc[t] = pcnt; __syncthreads();
    for (int off = 1; off < 256; off <<= 1) {
        int u = (t >= off) ? sc[t - off] : 0;
        __syncthreads();
        sc[t] += u;
        __syncthreads();
    }
    int mybeg = pbase + sc[t] - pcnt;
    cur[t] = mybeg;
    int nid = b * 256 + t;
    if (nid < NN) { rbeg[nid] = mybeg; rpend[nid] = mybeg + pcnt; }
    // fill padding with NN (zero row)
    for (int k = cnt; k < pcnt; ++k) col[mybeg + k] = NN;
    __syncthreads();
    for (int r = t; r < tot; r += 256) {
        u32 rc = rec[base + r];
        int slot = atomicAdd(&cur[rc >> 17], 1);
        col[slot] = (int)(rc & 0x1FFFFu);
    }
}

// ---------------- x (fp32) -> h16 ----------------

__global__ void cvt_kernel(const float* __restrict__ x, u32* __restrict__ h) {
    int i = blockIdx.x * blockDim.x + threadIdx.x;
    if (i < NN * 32) {
        float4 v = ((const float4*)x)[i];
        h[i * 2]     = f22h(v.x, v.y);
        h[i * 2 + 1] = f22h(v.z, v.w);
    }
}

// ---------------- aggregation: z16 = h16 + sum_{j in N(i)} h16[j] ----------------
// XCD column-sliced: block handles 16-col slice g = blockIdx%8 (== XCD under
// round-robin dispatch) of 32 nodes -> per-XCD h working set 3.2MB, L2-resident.
// Wave = 8 nodes x 8 lanes; per-lane-group edge loop (padded to mult of 4).

__global__ __launch_bounds__(256) void agg16_kernel(
    const u32* __restrict__ h, const int* __restrict__ rbeg,
    const int* __restrict__ rpend, const int* __restrict__ col,
    u32* __restrict__ z) {
    int g = blockIdx.x & 7;            // column group (u32 slice of 8)
    int chunk = blockIdx.x >> 3;
    int tid = threadIdx.x;
    int w = tid >> 6, lane = tid & 63;
    int k = lane >> 3;                 // node sub-index within wave
    int s = lane & 7;                  // u32 within slice
    int node = chunk * 32 + w * 8 + k; // NN = 3125*32 exactly
    const u32* hs = h + g * 8 + s;
    f16x2 sf = bc16x2(hs[(size_t)node * 64]);
    float ax = (float)sf[0], ay = (float)sf[1];
    int beg = rbeg[node], end = rpend[node];   // mult of 4
    for (int j = beg; j < end; j += 4) {
        int i0 = __builtin_nontemporal_load(&col[j]);
        int i1 = __builtin_nontemporal_load(&col[j + 1]);
        int i2 = __builtin_nontemporal_load(&col[j + 2]);
        int i3 = __builtin_nontemporal_load(&col[j + 3]);
        u32 v0 = hs[(size_t)i0 * 64];
        u32 v1 = hs[(size_t)i1 * 64];
        u32 v2 = hs[(size_t)i2 * 64];
        u32 v3 = hs[(size_t)i3 * 64];
        f16x2 t0 = bc16x2(v0) + bc16x2(v1);
        f16x2 t1 = bc16x2(v2) + bc16x2(v3);
        t0 = t0 + t1;
        ax += (float)t0[0]; ay += (float)t0[1];
    }
    __builtin_nontemporal_store(f22h(ax, ay), &z[(size_t)node * 64 + g * 8 + s]);
}

// ---------------- fused MLP + LayerNorm + ReLU ----------------

__device__ __forceinline__ void stage_w(const float* __restrict__ W, unsigned char* lds, int tid) {
    #pragma unroll
    for (int i = 0; i < 8; ++i) {
        int p = tid + i * 256;
        int c = p & 127;
        int k0 = (p >> 7) << 3;
        u16x8 t;
        #pragma unroll
        for (int j = 0; j < 8; ++j) t[j] = f2h_bits(W[(k0 + j) * 128 + c]);
        u32 off = ((((u32)c << 7) + k0) << 1) ^ (((u32)c & 7) << 4);
        *(u16x8*)(lds + off) = t;
    }
}

__global__ __launch_bounds__(256) void mlp_kernel(
    const u16* __restrict__ z16, const float* __restrict__ W1,
    const float* __restrict__ b1v, const float* __restrict__ W2,
    const float* __restrict__ b2v, const float* __restrict__ gam,
    const float* __restrict__ bet, u16* __restrict__ h16out,
    float* __restrict__ f32out)
{
    __shared__ __align__(16) unsigned char lds[49152];
    const int tid = threadIdx.x;
    const int lane = tid & 63;
    const int w = tid >> 6;
    const int rl = lane & 15;
    const int kg = lane >> 4;
    const int tile = blockIdx.x * 64;
    const int r0 = tile + w * 16;

    stage_w(W1, lds, tid);

    int zrow = r0 + rl; if (zrow > NN - 1) zrow = NN - 1;
    const u16* zp = z16 + (size_t)zrow * 128;
    f16x8 afr[4];
    #pragma unroll
    for (int kt = 0; kt < 4; ++kt)
        afr[kt] = *(const f16x8*)(zp + kt * 32 + kg * 8);
    __syncthreads();   // W1 staged

    #pragma unroll
    for (int nt = 0; nt < 8; ++nt) {
        f32x4 acc = {0.f, 0.f, 0.f, 0.f};
        int c = nt * 16 + rl;
        #pragma unroll
        for (int kt = 0; kt < 4; ++kt) {
            int kb = kt * 32 + kg * 8;
            u32 off = ((((u32)c << 7) + kb) << 1) ^ (((u32)c & 7) << 4);
            f16x8 b = *(const f16x8*)(lds + off);
            acc = __builtin_amdgcn_mfma_f32_16x16x32_f16(afr[kt], b, acc, 0, 0, 0);
        }
        float bias = b1v[c];
        #pragma unroll
        for (int r = 0; r < 4; ++r) {
            float v = acc[r] + bias;
            v = v > 0.f ? v : 0.f;
            int fullrow = w * 16 + kg * 4 + r;
            u32 hoff = 32768u + (((((u32)fullrow << 7) + c) << 1) ^ (((u32)fullrow & 7) << 4));
            *(u16*)(lds + hoff) = f2h_bits(v);
        }
    }

    __syncthreads();
    stage_w(W2, lds, tid);

    f16x8 afr2[4];
    int hrow = w * 16 + rl;
    #pragma unroll
    for (int kt = 0; kt < 4; ++kt) {
        int kb = kt * 32 + kg * 8;
        u32 off = 32768u + (((((u32)hrow << 7) + kb) << 1) ^ (((u32)hrow & 7) << 4));
        afr2[kt] = *(const f16x8*)(lds + off);
    }
    __syncthreads();

    f32x4 acc2[8];
    #pragma unroll
    for (int nt = 0; nt < 8; ++nt) {
        f32x4 acc = {0.f, 0.f, 0.f, 0.f};
        int c = nt * 16 + rl;
        #pragma unroll
        for (int kt = 0; kt < 4; ++kt) {
            int kb = kt * 32 + kg * 8;
            u32 off = ((((u32)c << 7) + kb) << 1) ^ (((u32)c & 7) << 4);
            f16x8 b = *(const f16x8*)(lds + off);
            acc = __builtin_amdgcn_mfma_f32_16x16x32_f16(afr2[kt], b, acc, 0, 0, 0);
        }
        float bias = b2v[c];
        acc[0] += bias; acc[1] += bias; acc[2] += bias; acc[3] += bias;
        acc2[nt] = acc;
    }

    float gamv[8], betv[8];
    #pragma unroll
    for (int nt = 0; nt < 8; ++nt) { gamv[nt] = gam[nt * 16 + rl]; betv[nt] = bet[nt * 16 + rl]; }
    #pragma unroll
    for (int r = 0; r < 4; ++r) {
        float s1 = 0.f, s2 = 0.f;
        #pragma unroll
        for (int nt = 0; nt < 8; ++nt) { float v = acc2[nt][r]; s1 += v; s2 += v * v; }
        #pragma unroll
        for (int m = 1; m < 16; m <<= 1) {
            s1 += __shfl_xor(s1, m, 64);
            s2 += __shfl_xor(s2, m, 64);
        }
        float mu = s1 * (1.f / 128.f);
        float var = s2 * (1.f / 128.f) - mu * mu;
        float rstd = rsqrtf(var + 1e-5f);
        int fullrow = r0 + kg * 4 + r;
        if (fullrow < NN) {
            #pragma unroll
            for (int nt = 0; nt < 8; ++nt) {
                float v = (acc2[nt][r] - mu) * rstd * gamv[nt] + betv[nt];
                v = v > 0.f ? v : 0.f;
                if (h16out) h16out[(size_t)fullrow * 128 + nt * 16 + rl] = f2h_bits(v);
                if (f32out) f32out[(size_t)fullrow * 128 + nt * 16 + rl] = v;
            }
        }
    }
}

// ---------------- host ----------------

extern "C" void kernel_launch(void* const* d_in, const int* in_sizes, int n_in,
                              void* d_out, int out_size, void* d_ws, size_t ws_size,
                              hipStream_t stream) {
    const float* x     = (const float*)d_in[0];
    const int*   ei    = (const int*)d_in[1];
    const float* W1    = (const float*)d_in[2];
    const float* b1    = (const float*)d_in[3];
    const float* W2    = (const float*)d_in[4];
    const float* b2    = (const float*)d_in[5];
    const float* gamma = (const float*)d_in[6];
    const float* beta  = (const float*)d_in[7];
    float* out = (float*)d_out;

    const int* src = ei;
    const int* dst = ei + EE;

    unsigned char* ws = (unsigned char*)d_ws;
    size_t off = 0;
    int* hist_g  = (int*)(ws + off); off += (size_t)NBUCK * NCHUNK * 4;
    int* bbase   = (int*)(ws + off); off += (size_t)(NBUCK + 1) * 4;
    int* rbeg    = (int*)(ws + off); off += (size_t)NN * 4;
    int* rpend   = (int*)(ws + off); off += (size_t)NN * 4; off = (off + 255) & ~(size_t)255;
    u32* rec     = (u32*)(ws + off); off += (size_t)EE * 4; off = (off + 255) & ~(size_t)255;
    int* colv    = (int*)(ws + off); off += ((size_t)EE + (size_t)NBUCK * PADMAX + 64) * 4;
    off = (off + 255) & ~(size_t)255;
    u32* h16a    = (u32*)(ws + off); off += (size_t)(NN + 1) * 64 * 4;
    u32* h16b    = (u32*)(ws + off); off += (size_t)(NN + 1) * 64 * 4;
    u32* z16     = (u32*)(ws + off); off += (size_t)NN * 64 * 4;

    csr_hist<<<NCHUNK, 1024, 0, stream>>>(dst, hist_g);
    csr_scan<<<1, 512, 0, stream>>>(hist_g, bbase);
    csr_scatter<<<NCHUNK, 1024, 0, stream>>>(src, dst, hist_g, rec);
    csr_finalize<<<NBUCK, 256, 0, stream>>>(rec, bbase, rbeg, rpend, colv);
    cvt_kernel<<<(NN * 32 + 255) / 256, 256, 0, stream>>>(x, h16a);
    // zero row NN of both h16 buffers (padding gathers land here)
    hipMemsetAsync(h16a + (size_t)NN * 64, 0, 256, stream);
    hipMemsetAsync(h16b + (size_t)NN * 64, 0, 256, stream);

    const u32* hin = h16a;
    u32* hnext = h16b;
    for (int l = 0; l < LL; ++l) {
        agg16_kernel<<<(NN / 32) * 8, 256, 0, stream>>>(hin, rbeg, rpend, colv, z16);
        mlp_kernel<<<(NN + 63) / 64, 256, 0, stream>>>(
            (const u16*)z16, W1 + (size_t)l * DD * DD, b1 + l * DD,
            W2 + (size_t)l * DD * DD, b2 + l * DD,
            gamma + l * DD, beta + l * DD,
            (l < LL - 1) ? (u16*)hnext : (u16*)nullptr,
            (l == LL - 1) ? out : (float*)nullptr);
        hin = hnext;
        hnext = (hnext == h16a) ? h16b : h16a;
    }
}

// Round 8
// 336.468 us; speedup vs baseline: 2.4086x; 2.4086x over previous
//
#include <hip/hip_runtime.h>

#define NN 100000
#define EE 1600000
#define DD 128
#define LL 3

typedef float f32x4 __attribute__((ext_vector_type(4)));
typedef _Float16 f16x8 __attribute__((ext_vector_type(8)));
typedef _Float16 f16x2 __attribute__((ext_vector_type(2)));
typedef unsigned short u16;
typedef unsigned int u32;
typedef u16 u16x8 __attribute__((ext_vector_type(8)));

// CSR-build geometry: buckets of 256 nodes, chunks of 16384 edges
#define NBUCK ((NN + 255) / 256)          // 391
#define CHUNK 16384
#define NCHUNK ((EE + CHUNK - 1) / CHUNK) // 98
#define PADMAX 1792                        // 256 nodes * 7 max pad per bucket

__device__ __forceinline__ u16 f2h_bits(float f) {
    _Float16 h = (_Float16)f;
    return __builtin_bit_cast(u16, h);
}
__device__ __forceinline__ f16x2 bc16x2(u32 v) {
    return __builtin_bit_cast(f16x2, v);
}
__device__ __forceinline__ u32 f22h(float x, float y) {
    return (u32)f2h_bits(x) | ((u32)f2h_bits(y) << 16);
}

// ---------------- CSR build: bucketed counting sort by dst ----------------

__global__ __launch_bounds__(1024) void csr_hist(const int* __restrict__ dst,
                                                 int* __restrict__ hist_g) {
    __shared__ int h[NBUCK];
    int t = threadIdx.x, c = blockIdx.x;
    for (int i = t; i < NBUCK; i += 1024) h[i] = 0;
    __syncthreads();
    int base = c * CHUNK;
    #pragma unroll
    for (int i = 0; i < CHUNK / 1024; ++i) {
        int e = base + t + i * 1024;
        if (e < EE) atomicAdd(&h[dst[e] >> 8], 1);
    }
    __syncthreads();
    for (int i = t; i < NBUCK; i += 1024) hist_g[i * NCHUNK + c] = h[i];
}

__global__ __launch_bounds__(512) void csr_scan(int* __restrict__ hist_g,
                                                int* __restrict__ bbase) {
    __shared__ int tot[512];
    int t = threadIdx.x;
    int sum = 0;
    if (t < NBUCK) {
        int* p = hist_g + t * NCHUNK;
        for (int c = 0; c < NCHUNK; ++c) { int v = p[c]; p[c] = sum; sum += v; }
    }
    tot[t] = sum; __syncthreads();
    for (int off = 1; off < 512; off <<= 1) {
        int u = (t >= off) ? tot[t - off] : 0;
        __syncthreads();
        tot[t] += u;
        __syncthreads();
    }
    int base = tot[t] - sum;   // exclusive
    if (t < NBUCK) {
        bbase[t] = base;
        int* p = hist_g + t * NCHUNK;
        for (int c = 0; c < NCHUNK; ++c) p[c] += base;
    }
    if (t == 0) bbase[NBUCK] = EE;
}

__global__ __launch_bounds__(1024) void csr_scatter(const int* __restrict__ src,
                                                    const int* __restrict__ dst,
                                                    const int* __restrict__ hist_g,
                                                    u32* __restrict__ rec) {
    __shared__ int cur[NBUCK];
    int t = threadIdx.x, c = blockIdx.x;
    for (int i = t; i < NBUCK; i += 1024) cur[i] = hist_g[i * NCHUNK + c];
    __syncthreads();
    int base = c * CHUNK;
    #pragma unroll
    for (int i = 0; i < CHUNK / 1024; ++i) {
        int e = base + t + i * 1024;
        if (e < EE) {
            int d = dst[e];
            int slot = atomicAdd(&cur[d >> 8], 1);
            rec[slot] = (u32)src[e] | ((u32)(d & 255) << 17);
        }
    }
}

// one block per bucket: padded (multiple-of-8) per-node segments, pad -> node NN
__global__ __launch_bounds__(256) void csr_finalize(const u32* __restrict__ rec,
                                                    const int* __restrict__ bbase,
                                                    int* __restrict__ rbeg,
                                                    int* __restrict__ rpend,
                                                    int* __restrict__ col) {
    __shared__ int cur[256];
    __shared__ int sc[256];
    int b = blockIdx.x, t = threadIdx.x;
    int base = bbase[b], tot = bbase[b + 1] - base;
    int pbase = base + b * PADMAX;
    sc[t] = 0; __syncthreads();
    for (int r = t; r < tot; r += 256) atomicAdd(&sc[rec[base + r] >> 17], 1);
    __syncthreads();
    int cnt = sc[t];
    int pcnt = (cnt + 7) & ~7;
    sc[t] = pcnt; __syncthreads();
    for (int off = 1; off < 256; off <<= 1) {
        int u = (t >= off) ? sc[t - off] : 0;
        __syncthreads();
        sc[t] += u;
        __syncthreads();
    }
    int mybeg = pbase + sc[t] - pcnt;
    cur[t] = mybeg;
    int nid = b * 256 + t;
    if (nid < NN) { rbeg[nid] = mybeg; rpend[nid] = mybeg + pcnt; }
    for (int k = cnt; k < pcnt; ++k) col[mybeg + k] = NN;   // pad -> zero row
    __syncthreads();
    for (int r = t; r < tot; r += 256) {
        u32 rc = rec[base + r];
        int slot = atomicAdd(&cur[rc >> 17], 1);
        col[slot] = (int)(rc & 0x1FFFFu);
    }
}

// ---------------- x (fp32) -> h16 ----------------

__global__ void cvt_kernel(const float* __restrict__ x, u32* __restrict__ h) {
    int i = blockIdx.x * blockDim.x + threadIdx.x;
    if (i < NN * 32) {
        float4 v = ((const float4*)x)[i];
        h[i * 2]     = f22h(v.x, v.y);
        h[i * 2 + 1] = f22h(v.z, v.w);
    }
}

// ---------------- W (fp32) -> pre-swizzled fp16 LDS images (one-time) ----------------
// image layout == mlp LDS layout: byte off = ((c<<7)+k0)<<1 ^ ((c&7)<<4)

__global__ __launch_bounds__(256) void wconv_kernel(const float* __restrict__ W1,
                                                    const float* __restrict__ W2,
                                                    u16* __restrict__ img) {
    int tt = blockIdx.x * 256 + threadIdx.x;    // 6 * 2048 = 12288 threads
    if (tt >= 6 * 2048) return;
    int m = tt >> 11;        // image 0..5: (layer l = m>>1, m&1 ? W2 : W1)
    int q = tt & 2047;
    int l = m >> 1;
    const float* W = ((m & 1) ? W2 : W1) + (size_t)l * DD * DD;
    int c = q & 127;
    int k0 = (q >> 7) << 3;
    u16x8 t;
    #pragma unroll
    for (int j = 0; j < 8; ++j) t[j] = f2h_bits(W[(k0 + j) * 128 + c]);
    u32 off = ((((u32)c << 7) + k0) << 1) ^ (((u32)c & 7) << 4);
    *(u16x8*)((unsigned char*)img + (size_t)m * 32768 + off) = t;
}

// ---------------- aggregation: z16 = h16 + sum_{j in N(i)} h16[j] ----------------
// one wave per node; lane c holds halves [2c,2c+1]; padded lists: 8 unconditional
// gathers per iter, fp16 pairwise-tree partial sum, fp32 master accumulator.

__global__ __launch_bounds__(256) void agg16_kernel(
    const u32* __restrict__ h, const int* __restrict__ rbeg,
    const int* __restrict__ rpend, const int* __restrict__ col,
    u32* __restrict__ z) {
    int node = blockIdx.x * 4 + (threadIdx.x >> 6);
    int c = threadIdx.x & 63;
    const u32* hp = h + c;
    f16x2 self = bc16x2(hp[(size_t)node * 64]);
    float accx = (float)self[0], accy = (float)self[1];
    int beg = rbeg[node], end = rpend[node];
    for (int j = beg; j < end; j += 8) {
        u32 v[8];
        #pragma unroll
        for (int q = 0; q < 8; ++q) v[q] = hp[(size_t)col[j + q] * 64];
        f16x2 s0 = bc16x2(v[0]) + bc16x2(v[1]);
        f16x2 s1 = bc16x2(v[2]) + bc16x2(v[3]);
        f16x2 s2 = bc16x2(v[4]) + bc16x2(v[5]);
        f16x2 s3 = bc16x2(v[6]) + bc16x2(v[7]);
        s0 = s0 + s1; s2 = s2 + s3; s0 = s0 + s2;
        accx += (float)s0[0]; accy += (float)s0[1];
    }
    z[(size_t)node * 64 + c] = f22h(accx, accy);
}

// ---------------- fused MLP + LayerNorm + ReLU ----------------
// LDS: [0,32768) W image (W1 then W2, phased), [32768,49152) hidden buffer.

__device__ __forceinline__ void stage_img(const u32* __restrict__ img,
                                          unsigned char* lds, int tid) {
    #pragma unroll
    for (int i = 0; i < 8; ++i) {
        int b = tid * 16 + i * 4096;
        *(uint4*)(lds + b) = *(const uint4*)((const unsigned char*)img + b);
    }
}

__global__ __launch_bounds__(256) void mlp_kernel(
    const u16* __restrict__ z16, const u32* __restrict__ img1,
    const float* __restrict__ b1v, const u32* __restrict__ img2,
    const float* __restrict__ b2v, const float* __restrict__ gam,
    const float* __restrict__ bet, u16* __restrict__ h16out,
    float* __restrict__ f32out)
{
    __shared__ __align__(16) unsigned char lds[49152];
    const int tid = threadIdx.x;
    const int lane = tid & 63;
    const int w = tid >> 6;
    const int rl = lane & 15;
    const int kg = lane >> 4;
    const int tile = blockIdx.x * 64;
    const int r0 = tile + w * 16;

    stage_img(img1, lds, tid);

    int zrow = r0 + rl; if (zrow > NN - 1) zrow = NN - 1;
    const u16* zp = z16 + (size_t)zrow * 128;
    f16x8 afr[4];
    #pragma unroll
    for (int kt = 0; kt < 4; ++kt)
        afr[kt] = *(const f16x8*)(zp + kt * 32 + kg * 8);
    __syncthreads();   // W1 staged

    #pragma unroll
    for (int nt = 0; nt < 8; ++nt) {
        f32x4 acc = {0.f, 0.f, 0.f, 0.f};
        int c = nt * 16 + rl;
        #pragma unroll
        for (int kt = 0; kt < 4; ++kt) {
            int kb = kt * 32 + kg * 8;
            u32 off = ((((u32)c << 7) + kb) << 1) ^ (((u32)c & 7) << 4);
            f16x8 b = *(const f16x8*)(lds + off);
            acc = __builtin_amdgcn_mfma_f32_16x16x32_f16(afr[kt], b, acc, 0, 0, 0);
        }
        float bias = b1v[c];
        #pragma unroll
        for (int r = 0; r < 4; ++r) {
            float v = acc[r] + bias;
            v = v > 0.f ? v : 0.f;
            int fullrow = w * 16 + kg * 4 + r;
            u32 hoff = 32768u + (((((u32)fullrow << 7) + c) << 1) ^ (((u32)fullrow & 7) << 4));
            *(u16*)(lds + hoff) = f2h_bits(v);
        }
    }

    __syncthreads();   // all W1 reads done
    stage_img(img2, lds, tid);

    f16x8 afr2[4];
    int hrow = w * 16 + rl;
    #pragma unroll
    for (int kt = 0; kt < 4; ++kt) {
        int kb = kt * 32 + kg * 8;
        u32 off = 32768u + (((((u32)hrow << 7) + kb) << 1) ^ (((u32)hrow & 7) << 4));
        afr2[kt] = *(const f16x8*)(lds + off);
    }
    __syncthreads();   // W2 staged

    f32x4 acc2[8];
    #pragma unroll
    for (int nt = 0; nt < 8; ++nt) {
        f32x4 acc = {0.f, 0.f, 0.f, 0.f};
        int c = nt * 16 + rl;
        #pragma unroll
        for (int kt = 0; kt < 4; ++kt) {
            int kb = kt * 32 + kg * 8;
            u32 off = ((((u32)c << 7) + kb) << 1) ^ (((u32)c & 7) << 4);
            f16x8 b = *(const f16x8*)(lds + off);
            acc = __builtin_amdgcn_mfma_f32_16x16x32_f16(afr2[kt], b, acc, 0, 0, 0);
        }
        float bias = b2v[c];
        acc[0] += bias; acc[1] += bias; acc[2] += bias; acc[3] += bias;
        acc2[nt] = acc;
    }

    float gamv[8], betv[8];
    #pragma unroll
    for (int nt = 0; nt < 8; ++nt) { gamv[nt] = gam[nt * 16 + rl]; betv[nt] = bet[nt * 16 + rl]; }
    #pragma unroll
    for (int r = 0; r < 4; ++r) {
        float s1 = 0.f, s2 = 0.f;
        #pragma unroll
        for (int nt = 0; nt < 8; ++nt) { float v = acc2[nt][r]; s1 += v; s2 += v * v; }
        #pragma unroll
        for (int m = 1; m < 16; m <<= 1) {
            s1 += __shfl_xor(s1, m, 64);
            s2 += __shfl_xor(s2, m, 64);
        }
        float mu = s1 * (1.f / 128.f);
        float var = s2 * (1.f / 128.f) - mu * mu;
        float rstd = rsqrtf(var + 1e-5f);
        int fullrow = r0 + kg * 4 + r;
        if (fullrow < NN) {
            #pragma unroll
            for (int nt = 0; nt < 8; ++nt) {
                float v = (acc2[nt][r] - mu) * rstd * gamv[nt] + betv[nt];
                v = v > 0.f ? v : 0.f;
                if (h16out) h16out[(size_t)fullrow * 128 + nt * 16 + rl] = f2h_bits(v);
                if (f32out) f32out[(size_t)fullrow * 128 + nt * 16 + rl] = v;
            }
        }
    }
}

// ---------------- host ----------------

extern "C" void kernel_launch(void* const* d_in, const int* in_sizes, int n_in,
                              void* d_out, int out_size, void* d_ws, size_t ws_size,
                              hipStream_t stream) {
    const float* x     = (const float*)d_in[0];
    const int*   ei    = (const int*)d_in[1];
    const float* W1    = (const float*)d_in[2];
    const float* b1    = (const float*)d_in[3];
    const float* W2    = (const float*)d_in[4];
    const float* b2    = (const float*)d_in[5];
    const float* gamma = (const float*)d_in[6];
    const float* beta  = (const float*)d_in[7];
    float* out = (float*)d_out;

    const int* src = ei;
    const int* dst = ei + EE;

    unsigned char* ws = (unsigned char*)d_ws;
    size_t off = 0;
    int* hist_g  = (int*)(ws + off); off += (size_t)NBUCK * NCHUNK * 4;
    int* bbase   = (int*)(ws + off); off += (size_t)(NBUCK + 1) * 4;
    int* rbeg    = (int*)(ws + off); off += (size_t)NN * 4;
    int* rpend   = (int*)(ws + off); off += (size_t)NN * 4; off = (off + 255) & ~(size_t)255;
    u16* wimg    = (u16*)(ws + off); off += (size_t)6 * 16384 * 2; off = (off + 255) & ~(size_t)255;
    u32* rec     = (u32*)(ws + off); off += (size_t)EE * 4; off = (off + 255) & ~(size_t)255;
    int* colv    = (int*)(ws + off); off += ((size_t)EE + (size_t)NBUCK * PADMAX + 64) * 4;
    off = (off + 255) & ~(size_t)255;
    u32* h16a    = (u32*)(ws + off); off += (size_t)(NN + 1) * 64 * 4;
    u32* h16b    = (u32*)(ws + off); off += (size_t)(NN + 1) * 64 * 4;
    u32* z16     = (u32*)(ws + off); off += (size_t)NN * 64 * 4;

    csr_hist<<<NCHUNK, 1024, 0, stream>>>(dst, hist_g);
    csr_scan<<<1, 512, 0, stream>>>(hist_g, bbase);
    csr_scatter<<<NCHUNK, 1024, 0, stream>>>(src, dst, hist_g, rec);
    csr_finalize<<<NBUCK, 256, 0, stream>>>(rec, bbase, rbeg, rpend, colv);
    wconv_kernel<<<48, 256, 0, stream>>>(W1, W2, wimg);
    cvt_kernel<<<(NN * 32 + 255) / 256, 256, 0, stream>>>(x, h16a);
    // zero row NN of both h16 buffers (padding gathers land here)
    hipMemsetAsync(h16a + (size_t)NN * 64, 0, 256, stream);
    hipMemsetAsync(h16b + (size_t)NN * 64, 0, 256, stream);

    const u32* hin = h16a;
    u32* hnext = h16b;
    for (int l = 0; l < LL; ++l) {
        agg16_kernel<<<NN / 4, 256, 0, stream>>>(hin, rbeg, rpend, colv, z16);
        mlp_kernel<<<(NN + 63) / 64, 256, 0, stream>>>(
            (const u16*)z16,
            (const u32*)(wimg + (size_t)(2 * l) * 16384), b1 + l * DD,
            (const u32*)(wimg + (size_t)(2 * l + 1) * 16384), b2 + l * DD,
            gamma + l * DD, beta + l * DD,
            (l < LL - 1) ? (u16*)hnext : (u16*)nullptr,
            (l == LL - 1) ? out : (float*)nullptr);
        hin = hnext;
        hnext = (hnext == h16a) ? h16b : h16a;
    }
}

// Round 9
// 311.307 us; speedup vs baseline: 2.6032x; 1.0808x over previous
//
#include <hip/hip_runtime.h>

#define NN 100000
#define EE 1600000
#define DD 128
#define LL 3

typedef float f32x4 __attribute__((ext_vector_type(4)));
typedef _Float16 f16x8 __attribute__((ext_vector_type(8)));
typedef _Float16 f16x2 __attribute__((ext_vector_type(2)));
typedef unsigned short u16;
typedef unsigned int u32;
typedef u16 u16x8 __attribute__((ext_vector_type(8)));

// CSR-build geometry: buckets of 256 nodes, chunks of 16384 edges
#define NBUCK ((NN + 255) / 256)          // 391
#define CHUNK 16384
#define NCHUNK ((EE + CHUNK - 1) / CHUNK) // 98
#define PADMAX 768                         // 256 nodes * 3 max pad (mult-4)

__device__ __forceinline__ u16 f2h_bits(float f) {
    _Float16 h = (_Float16)f;
    return __builtin_bit_cast(u16, h);
}
__device__ __forceinline__ f16x2 bc16x2(u32 v) {
    return __builtin_bit_cast(f16x2, v);
}
__device__ __forceinline__ u32 f22h(float x, float y) {
    return (u32)f2h_bits(x) | ((u32)f2h_bits(y) << 16);
}

// ---------------- CSR build: bucketed counting sort by dst ----------------

__global__ __launch_bounds__(1024) void csr_hist(const int* __restrict__ dst,
                                                 int* __restrict__ hist_g) {
    __shared__ int h[NBUCK];
    int t = threadIdx.x, c = blockIdx.x;
    for (int i = t; i < NBUCK; i += 1024) h[i] = 0;
    __syncthreads();
    int base = c * CHUNK;
    #pragma unroll
    for (int i = 0; i < CHUNK / 1024; ++i) {
        int e = base + t + i * 1024;
        if (e < EE) atomicAdd(&h[dst[e] >> 8], 1);
    }
    __syncthreads();
    for (int i = t; i < NBUCK; i += 1024) hist_g[i * NCHUNK + c] = h[i];
}

// per-bucket exclusive scan of its chunk counts (in place) + bucket total
__global__ __launch_bounds__(128) void csr_scanA(int* __restrict__ hist_g,
                                                 int* __restrict__ btot) {
    __shared__ int sh[128];
    int b = blockIdx.x, t = threadIdx.x;
    int v = (t < NCHUNK) ? hist_g[b * NCHUNK + t] : 0;
    sh[t] = v; __syncthreads();
    for (int off = 1; off < 128; off <<= 1) {
        int u = (t >= off) ? sh[t - off] : 0;
        __syncthreads();
        sh[t] += u;
        __syncthreads();
    }
    if (t < NCHUNK) hist_g[b * NCHUNK + t] = sh[t] - v;
    if (t == 127) btot[b] = sh[127];
}

// single small block: exclusive scan of bucket totals
__global__ __launch_bounds__(512) void csr_scanB(const int* __restrict__ btot,
                                                 int* __restrict__ bbase) {
    __shared__ int sh[512];
    int t = threadIdx.x;
    int v = (t < NBUCK) ? btot[t] : 0;
    sh[t] = v; __syncthreads();
    for (int off = 1; off < 512; off <<= 1) {
        int u = (t >= off) ? sh[t - off] : 0;
        __syncthreads();
        sh[t] += u;
        __syncthreads();
    }
    if (t < NBUCK) bbase[t] = sh[t] - v;
    if (t == 0) bbase[NBUCK] = EE;
}

__global__ __launch_bounds__(1024) void csr_scatter(const int* __restrict__ src,
                                                    const int* __restrict__ dst,
                                                    const int* __restrict__ hist_g,
                                                    const int* __restrict__ bbase,
                                                    u32* __restrict__ rec) {
    __shared__ int cur[NBUCK];
    int t = threadIdx.x, c = blockIdx.x;
    for (int i = t; i < NBUCK; i += 1024) cur[i] = bbase[i] + hist_g[i * NCHUNK + c];
    __syncthreads();
    int base = c * CHUNK;
    #pragma unroll
    for (int i = 0; i < CHUNK / 1024; ++i) {
        int e = base + t + i * 1024;
        if (e < EE) {
            int d = dst[e];
            int slot = atomicAdd(&cur[d >> 8], 1);
            rec[slot] = (u32)src[e] | ((u32)(d & 255) << 17);
        }
    }
}

// one block per bucket: padded (multiple-of-4) per-node segments, pad -> node NN
__global__ __launch_bounds__(256) void csr_finalize(const u32* __restrict__ rec,
                                                    const int* __restrict__ bbase,
                                                    int* __restrict__ rbeg,
                                                    int* __restrict__ rpend,
                                                    int* __restrict__ col) {
    __shared__ int cur[256];
    __shared__ int sc[256];
    int b = blockIdx.x, t = threadIdx.x;
    int base = bbase[b], tot = bbase[b + 1] - base;
    int pbase = base + b * PADMAX;
    sc[t] = 0; __syncthreads();
    for (int r = t; r < tot; r += 256) atomicAdd(&sc[rec[base + r] >> 17], 1);
    __syncthreads();
    int cnt = sc[t];
    int pcnt = (cnt + 3) & ~3;
    sc[t] = pcnt; __syncthreads();
    for (int off = 1; off < 256; off <<= 1) {
        int u = (t >= off) ? sc[t - off] : 0;
        __syncthreads();
        sc[t] += u;
        __syncthreads();
    }
    int mybeg = pbase + sc[t] - pcnt;
    cur[t] = mybeg;
    int nid = b * 256 + t;
    if (nid < NN) { rbeg[nid] = mybeg; rpend[nid] = mybeg + pcnt; }
    for (int k = cnt; k < pcnt; ++k) col[mybeg + k] = NN;   // pad -> zero row
    __syncthreads();
    for (int r = t; r < tot; r += 256) {
        u32 rc = rec[base + r];
        int slot = atomicAdd(&cur[rc >> 17], 1);
        col[slot] = (int)(rc & 0x1FFFFu);
    }
}

// ---------------- x (fp32) -> h16, plus zero row NN of both h buffers ----------------

__global__ void cvt_kernel(const float* __restrict__ x, u32* __restrict__ ha,
                           u32* __restrict__ hb) {
    int i = blockIdx.x * blockDim.x + threadIdx.x;
    if (i < NN * 32) {
        float4 v = ((const float4*)x)[i];
        ha[i * 2]     = f22h(v.x, v.y);
        ha[i * 2 + 1] = f22h(v.z, v.w);
    } else {
        int k = i - NN * 32;
        if (k < 64) {
            ha[(size_t)NN * 64 + k] = 0;
            hb[(size_t)NN * 64 + k] = 0;
        }
    }
}

// ---------------- W (fp32) -> pre-swizzled fp16 LDS images (one-time) ----------------

__global__ __launch_bounds__(256) void wconv_kernel(const float* __restrict__ W1,
                                                    const float* __restrict__ W2,
                                                    u16* __restrict__ img) {
    int tt = blockIdx.x * 256 + threadIdx.x;    // 6 * 2048 = 12288 threads
    if (tt >= 6 * 2048) return;
    int m = tt >> 11;        // image 0..5: (layer l = m>>1, m&1 ? W2 : W1)
    int q = tt & 2047;
    int l = m >> 1;
    const float* W = ((m & 1) ? W2 : W1) + (size_t)l * DD * DD;
    int c = q & 127;
    int k0 = (q >> 7) << 3;
    u16x8 t;
    #pragma unroll
    for (int j = 0; j < 8; ++j) t[j] = f2h_bits(W[(k0 + j) * 128 + c]);
    u32 off = ((((u32)c << 7) + k0) << 1) ^ (((u32)c & 7) << 4);
    *(u16x8*)((unsigned char*)img + (size_t)m * 32768 + off) = t;
}

// ---------------- aggregation: z16 = h16 + sum_{j in N(i)} h16[j] ----------------
// one wave per node; lane c holds halves [2c,2c+1]; lists padded to mult-4.
// Main loop: 8 unconditional gathers in flight; tail: one 4-group.

__global__ __launch_bounds__(256) void agg16_kernel(
    const u32* __restrict__ h, const int* __restrict__ rbeg,
    const int* __restrict__ rpend, const int* __restrict__ col,
    u32* __restrict__ z) {
    int node = blockIdx.x * 4 + (threadIdx.x >> 6);
    int c = threadIdx.x & 63;
    const u32* hp = h + c;
    f16x2 self = bc16x2(hp[(size_t)node * 64]);
    float accx = (float)self[0], accy = (float)self[1];
    int beg = rbeg[node], end = rpend[node];
    int j = beg;
    for (; j + 8 <= end; j += 8) {
        u32 v[8];
        #pragma unroll
        for (int q = 0; q < 8; ++q) v[q] = hp[(size_t)col[j + q] * 64];
        f16x2 s0 = bc16x2(v[0]) + bc16x2(v[1]);
        f16x2 s1 = bc16x2(v[2]) + bc16x2(v[3]);
        f16x2 s2 = bc16x2(v[4]) + bc16x2(v[5]);
        f16x2 s3 = bc16x2(v[6]) + bc16x2(v[7]);
        s0 = s0 + s1; s2 = s2 + s3; s0 = s0 + s2;
        accx += (float)s0[0]; accy += (float)s0[1];
    }
    if (j < end) {   // exactly 4 remain
        u32 v0 = hp[(size_t)col[j] * 64];
        u32 v1 = hp[(size_t)col[j + 1] * 64];
        u32 v2 = hp[(size_t)col[j + 2] * 64];
        u32 v3 = hp[(size_t)col[j + 3] * 64];
        f16x2 t0 = bc16x2(v0) + bc16x2(v1);
        f16x2 t1 = bc16x2(v2) + bc16x2(v3);
        t0 = t0 + t1;
        accx += (float)t0[0]; accy += (float)t0[1];
    }
    z[(size_t)node * 64 + c] = f22h(accx, accy);
}

// ---------------- fused MLP + LayerNorm + ReLU ----------------
// 512 threads = 8 waves; M-tile = 128 rows; wave w owns rows w*16..w*16+15.
// LDS: [0,32768) W image (W1 then W2, phased), [32768,65536) hidden buffer.

__device__ __forceinline__ void stage_img(const u32* __restrict__ img,
                                          unsigned char* lds, int tid) {
    #pragma unroll
    for (int i = 0; i < 4; ++i) {
        int b = tid * 16 + i * 8192;
        *(uint4*)(lds + b) = *(const uint4*)((const unsigned char*)img + b);
    }
}

__global__ __launch_bounds__(512) void mlp_kernel(
    const u16* __restrict__ z16, const u32* __restrict__ img1,
    const float* __restrict__ b1v, const u32* __restrict__ img2,
    const float* __restrict__ b2v, const float* __restrict__ gam,
    const float* __restrict__ bet, u16* __restrict__ h16out,
    float* __restrict__ f32out)
{
    __shared__ __align__(16) unsigned char lds[65536];
    const int tid = threadIdx.x;
    const int lane = tid & 63;
    const int w = tid >> 6;       // wave 0..7
    const int rl = lane & 15;
    const int kg = lane >> 4;
    const int tile = blockIdx.x * 128;
    const int r0 = tile + w * 16;

    stage_img(img1, lds, tid);

    int zrow = r0 + rl; if (zrow > NN - 1) zrow = NN - 1;
    const u16* zp = z16 + (size_t)zrow * 128;
    f16x8 afr[4];
    #pragma unroll
    for (int kt = 0; kt < 4; ++kt)
        afr[kt] = *(const f16x8*)(zp + kt * 32 + kg * 8);
    __syncthreads();   // W1 staged

    #pragma unroll
    for (int nt = 0; nt < 8; ++nt) {
        f32x4 acc = {0.f, 0.f, 0.f, 0.f};
        int c = nt * 16 + rl;
        #pragma unroll
        for (int kt = 0; kt < 4; ++kt) {
            int kb = kt * 32 + kg * 8;
            u32 off = ((((u32)c << 7) + kb) << 1) ^ (((u32)c & 7) << 4);
            f16x8 b = *(const f16x8*)(lds + off);
            acc = __builtin_amdgcn_mfma_f32_16x16x32_f16(afr[kt], b, acc, 0, 0, 0);
        }
        float bias = b1v[c];
        #pragma unroll
        for (int r = 0; r < 4; ++r) {
            float v = acc[r] + bias;
            v = v > 0.f ? v : 0.f;
            int fullrow = w * 16 + kg * 4 + r;     // 0..127
            u32 hoff = 32768u + (((((u32)fullrow << 7) + c) << 1) ^ (((u32)fullrow & 7) << 4));
            *(u16*)(lds + hoff) = f2h_bits(v);
        }
    }

    __syncthreads();   // all W1 reads done
    stage_img(img2, lds, tid);

    f16x8 afr2[4];
    int hrow = w * 16 + rl;
    #pragma unroll
    for (int kt = 0; kt < 4; ++kt) {
        int kb = kt * 32 + kg * 8;
        u32 off = 32768u + (((((u32)hrow << 7) + kb) << 1) ^ (((u32)hrow & 7) << 4));
        afr2[kt] = *(const f16x8*)(lds + off);
    }
    __syncthreads();   // W2 staged

    f32x4 acc2[8];
    #pragma unroll
    for (int nt = 0; nt < 8; ++nt) {
        f32x4 acc = {0.f, 0.f, 0.f, 0.f};
        int c = nt * 16 + rl;
        #pragma unroll
        for (int kt = 0; kt < 4; ++kt) {
            int kb = kt * 32 + kg * 8;
            u32 off = ((((u32)c << 7) + kb) << 1) ^ (((u32)c & 7) << 4);
            f16x8 b = *(const f16x8*)(lds + off);
            acc = __builtin_amdgcn_mfma_f32_16x16x32_f16(afr2[kt], b, acc, 0, 0, 0);
        }
        float bias = b2v[c];
        acc[0] += bias; acc[1] += bias; acc[2] += bias; acc[3] += bias;
        acc2[nt] = acc;
    }

    float gamv[8], betv[8];
    #pragma unroll
    for (int nt = 0; nt < 8; ++nt) { gamv[nt] = gam[nt * 16 + rl]; betv[nt] = bet[nt * 16 + rl]; }
    #pragma unroll
    for (int r = 0; r < 4; ++r) {
        float s1 = 0.f, s2 = 0.f;
        #pragma unroll
        for (int nt = 0; nt < 8; ++nt) { float v = acc2[nt][r]; s1 += v; s2 += v * v; }
        #pragma unroll
        for (int m = 1; m < 16; m <<= 1) {
            s1 += __shfl_xor(s1, m, 64);
            s2 += __shfl_xor(s2, m, 64);
        }
        float mu = s1 * (1.f / 128.f);
        float var = s2 * (1.f / 128.f) - mu * mu;
        float rstd = rsqrtf(var + 1e-5f);
        int fullrow = r0 + kg * 4 + r;
        if (fullrow < NN) {
            #pragma unroll
            for (int nt = 0; nt < 8; ++nt) {
                float v = (acc2[nt][r] - mu) * rstd * gamv[nt] + betv[nt];
                v = v > 0.f ? v : 0.f;
                if (h16out) h16out[(size_t)fullrow * 128 + nt * 16 + rl] = f2h_bits(v);
                if (f32out) f32out[(size_t)fullrow * 128 + nt * 16 + rl] = v;
            }
        }
    }
}

// ---------------- host ----------------

extern "C" void kernel_launch(void* const* d_in, const int* in_sizes, int n_in,
                              void* d_out, int out_size, void* d_ws, size_t ws_size,
                              hipStream_t stream) {
    const float* x     = (const float*)d_in[0];
    const int*   ei    = (const int*)d_in[1];
    const float* W1    = (const float*)d_in[2];
    const float* b1    = (const float*)d_in[3];
    const float* W2    = (const float*)d_in[4];
    const float* b2    = (const float*)d_in[5];
    const float* gamma = (const float*)d_in[6];
    const float* beta  = (const float*)d_in[7];
    float* out = (float*)d_out;

    const int* src = ei;
    const int* dst = ei + EE;

    unsigned char* ws = (unsigned char*)d_ws;
    size_t off = 0;
    int* hist_g  = (int*)(ws + off); off += (size_t)NBUCK * NCHUNK * 4;
    int* btot    = (int*)(ws + off); off += (size_t)(NBUCK + 1) * 4;
    int* bbase   = (int*)(ws + off); off += (size_t)(NBUCK + 1) * 4;
    int* rbeg    = (int*)(ws + off); off += (size_t)NN * 4;
    int* rpend   = (int*)(ws + off); off += (size_t)NN * 4; off = (off + 255) & ~(size_t)255;
    u16* wimg    = (u16*)(ws + off); off += (size_t)6 * 16384 * 2; off = (off + 255) & ~(size_t)255;
    u32* rec     = (u32*)(ws + off); off += (size_t)EE * 4; off = (off + 255) & ~(size_t)255;
    int* colv    = (int*)(ws + off); off += ((size_t)EE + (size_t)NBUCK * PADMAX + 64) * 4;
    off = (off + 255) & ~(size_t)255;
    u32* h16a    = (u32*)(ws + off); off += (size_t)(NN + 1) * 64 * 4;
    u32* h16b    = (u32*)(ws + off); off += (size_t)(NN + 1) * 64 * 4;
    u32* z16     = (u32*)(ws + off); off += (size_t)NN * 64 * 4;

    csr_hist<<<NCHUNK, 1024, 0, stream>>>(dst, hist_g);
    csr_scanA<<<NBUCK, 128, 0, stream>>>(hist_g, btot);
    csr_scanB<<<1, 512, 0, stream>>>(btot, bbase);
    csr_scatter<<<NCHUNK, 1024, 0, stream>>>(src, dst, hist_g, bbase, rec);
    csr_finalize<<<NBUCK, 256, 0, stream>>>(rec, bbase, rbeg, rpend, colv);
    wconv_kernel<<<48, 256, 0, stream>>>(W1, W2, wimg);
    cvt_kernel<<<NN * 32 / 256 + 1, 256, 0, stream>>>(x, h16a, h16b);

    const u32* hin = h16a;
    u32* hnext = h16b;
    for (int l = 0; l < LL; ++l) {
        agg16_kernel<<<NN / 4, 256, 0, stream>>>(hin, rbeg, rpend, colv, z16);
        mlp_kernel<<<(NN + 127) / 128, 512, 0, stream>>>(
            (const u16*)z16,
            (const u32*)(wimg + (size_t)(2 * l) * 16384), b1 + l * DD,
            (const u32*)(wimg + (size_t)(2 * l + 1) * 16384), b2 + l * DD,
            gamma + l * DD, beta + l * DD,
            (l < LL - 1) ? (u16*)hnext : (u16*)nullptr,
            (l == LL - 1) ? out : (float*)nullptr);
        hin = hnext;
        hnext = (hnext == h16a) ? h16b : h16a;
    }
}

// Round 10
// 309.747 us; speedup vs baseline: 2.6163x; 1.0050x over previous
//
#include <hip/hip_runtime.h>

#define NN 100000
#define EE 1600000
#define DD 128
#define LL 3

typedef float f32x4 __attribute__((ext_vector_type(4)));
typedef _Float16 f16x8 __attribute__((ext_vector_type(8)));
typedef _Float16 f16x2 __attribute__((ext_vector_type(2)));
typedef unsigned short u16;
typedef unsigned int u32;
typedef u16 u16x8 __attribute__((ext_vector_type(8)));

// CSR-build geometry: buckets of 256 nodes, chunks of 16384 edges
#define NBUCK ((NN + 255) / 256)          // 391
#define CHUNK 16384
#define NCHUNK ((EE + CHUNK - 1) / CHUNK) // 98
#define PADMAX 768                         // 256 nodes * 3 max pad (mult-4)

__device__ __forceinline__ u16 f2h_bits(float f) {
    _Float16 h = (_Float16)f;
    return __builtin_bit_cast(u16, h);
}
__device__ __forceinline__ f16x2 bc16x2(u32 v) {
    return __builtin_bit_cast(f16x2, v);
}
__device__ __forceinline__ u32 f22h(float x, float y) {
    return (u32)f2h_bits(x) | ((u32)f2h_bits(y) << 16);
}

// ---------------- CSR build: bucketed counting sort by dst ----------------

__global__ __launch_bounds__(1024) void csr_hist(const int* __restrict__ dst,
                                                 int* __restrict__ hist_g) {
    __shared__ int h[NBUCK];
    int t = threadIdx.x, c = blockIdx.x;
    for (int i = t; i < NBUCK; i += 1024) h[i] = 0;
    __syncthreads();
    int base = c * CHUNK;
    #pragma unroll
    for (int i = 0; i < CHUNK / 1024; ++i) {
        int e = base + t + i * 1024;
        if (e < EE) atomicAdd(&h[dst[e] >> 8], 1);
    }
    __syncthreads();
    for (int i = t; i < NBUCK; i += 1024) hist_g[i * NCHUNK + c] = h[i];
}

// per-bucket exclusive scan of its chunk counts (in place) + bucket total
__global__ __launch_bounds__(128) void csr_scanA(int* __restrict__ hist_g,
                                                 int* __restrict__ btot) {
    __shared__ int sh[128];
    int b = blockIdx.x, t = threadIdx.x;
    int v = (t < NCHUNK) ? hist_g[b * NCHUNK + t] : 0;
    sh[t] = v; __syncthreads();
    for (int off = 1; off < 128; off <<= 1) {
        int u = (t >= off) ? sh[t - off] : 0;
        __syncthreads();
        sh[t] += u;
        __syncthreads();
    }
    if (t < NCHUNK) hist_g[b * NCHUNK + t] = sh[t] - v;
    if (t == 127) btot[b] = sh[127];
}

// single small block: exclusive scan of bucket totals
__global__ __launch_bounds__(512) void csr_scanB(const int* __restrict__ btot,
                                                 int* __restrict__ bbase) {
    __shared__ int sh[512];
    int t = threadIdx.x;
    int v = (t < NBUCK) ? btot[t] : 0;
    sh[t] = v; __syncthreads();
    for (int off = 1; off < 512; off <<= 1) {
        int u = (t >= off) ? sh[t - off] : 0;
        __syncthreads();
        sh[t] += u;
        __syncthreads();
    }
    if (t < NBUCK) bbase[t] = sh[t] - v;
    if (t == 0) bbase[NBUCK] = EE;
}

__global__ __launch_bounds__(1024) void csr_scatter(const int* __restrict__ src,
                                                    const int* __restrict__ dst,
                                                    const int* __restrict__ hist_g,
                                                    const int* __restrict__ bbase,
                                                    u32* __restrict__ rec) {
    __shared__ int cur[NBUCK];
    int t = threadIdx.x, c = blockIdx.x;
    for (int i = t; i < NBUCK; i += 1024) cur[i] = bbase[i] + hist_g[i * NCHUNK + c];
    __syncthreads();
    int base = c * CHUNK;
    #pragma unroll
    for (int i = 0; i < CHUNK / 1024; ++i) {
        int e = base + t + i * 1024;
        if (e < EE) {
            int d = dst[e];
            int slot = atomicAdd(&cur[d >> 8], 1);
            rec[slot] = (u32)src[e] | ((u32)(d & 255) << 17);
        }
    }
}

// one block per bucket: padded (multiple-of-4) per-node segments, pad -> node NN
__global__ __launch_bounds__(256) void csr_finalize(const u32* __restrict__ rec,
                                                    const int* __restrict__ bbase,
                                                    int* __restrict__ rbeg,
                                                    int* __restrict__ rpend,
                                                    int* __restrict__ col) {
    __shared__ int cur[256];
    __shared__ int sc[256];
    int b = blockIdx.x, t = threadIdx.x;
    int base = bbase[b], tot = bbase[b + 1] - base;
    int pbase = base + b * PADMAX;
    sc[t] = 0; __syncthreads();
    for (int r = t; r < tot; r += 256) atomicAdd(&sc[rec[base + r] >> 17], 1);
    __syncthreads();
    int cnt = sc[t];
    int pcnt = (cnt + 3) & ~3;
    sc[t] = pcnt; __syncthreads();
    for (int off = 1; off < 256; off <<= 1) {
        int u = (t >= off) ? sc[t - off] : 0;
        __syncthreads();
        sc[t] += u;
        __syncthreads();
    }
    int mybeg = pbase + sc[t] - pcnt;
    cur[t] = mybeg;
    int nid = b * 256 + t;
    if (nid < NN) { rbeg[nid] = mybeg; rpend[nid] = mybeg + pcnt; }
    for (int k = cnt; k < pcnt; ++k) col[mybeg + k] = NN;   // pad -> zero row
    __syncthreads();
    for (int r = t; r < tot; r += 256) {
        u32 rc = rec[base + r];
        int slot = atomicAdd(&cur[rc >> 17], 1);
        col[slot] = (int)(rc & 0x1FFFFu);
    }
}

// ---------------- x (fp32) -> h16, plus zero row NN of both h buffers ----------------

__global__ void cvt_kernel(const float* __restrict__ x, u32* __restrict__ ha,
                           u32* __restrict__ hb) {
    int i = blockIdx.x * blockDim.x + threadIdx.x;
    if (i < NN * 32) {
        float4 v = ((const float4*)x)[i];
        ha[i * 2]     = f22h(v.x, v.y);
        ha[i * 2 + 1] = f22h(v.z, v.w);
    } else {
        int k = i - NN * 32;
        if (k < 64) {
            ha[(size_t)NN * 64 + k] = 0;
            hb[(size_t)NN * 64 + k] = 0;
        }
    }
}

// ---------------- W (fp32) -> pre-swizzled fp16 LDS images (one-time) ----------------
// image m = (layer l = m>>1, m&1 ? W2 : W1); per-layer pair is contiguous 64KB.

__global__ __launch_bounds__(256) void wconv_kernel(const float* __restrict__ W1,
                                                    const float* __restrict__ W2,
                                                    u16* __restrict__ img) {
    int tt = blockIdx.x * 256 + threadIdx.x;    // 6 * 2048 = 12288 threads
    if (tt >= 6 * 2048) return;
    int m = tt >> 11;
    int q = tt & 2047;
    int l = m >> 1;
    const float* W = ((m & 1) ? W2 : W1) + (size_t)l * DD * DD;
    int c = q & 127;
    int k0 = (q >> 7) << 3;
    u16x8 t;
    #pragma unroll
    for (int j = 0; j < 8; ++j) t[j] = f2h_bits(W[(k0 + j) * 128 + c]);
    u32 off = ((((u32)c << 7) + k0) << 1) ^ (((u32)c & 7) << 4);
    *(u16x8*)((unsigned char*)img + (size_t)m * 32768 + off) = t;
}

// ---------------- aggregation: z16 = h16 + sum_{j in N(i)} h16[j] ----------------

__global__ __launch_bounds__(256) void agg16_kernel(
    const u32* __restrict__ h, const int* __restrict__ rbeg,
    const int* __restrict__ rpend, const int* __restrict__ col,
    u32* __restrict__ z) {
    int node = blockIdx.x * 4 + (threadIdx.x >> 6);
    int c = threadIdx.x & 63;
    const u32* hp = h + c;
    f16x2 self = bc16x2(hp[(size_t)node * 64]);
    float accx = (float)self[0], accy = (float)self[1];
    int beg = rbeg[node], end = rpend[node];
    int j = beg;
    for (; j + 8 <= end; j += 8) {
        u32 v[8];
        #pragma unroll
        for (int q = 0; q < 8; ++q) v[q] = hp[(size_t)col[j + q] * 64];
        f16x2 s0 = bc16x2(v[0]) + bc16x2(v[1]);
        f16x2 s1 = bc16x2(v[2]) + bc16x2(v[3]);
        f16x2 s2 = bc16x2(v[4]) + bc16x2(v[5]);
        f16x2 s3 = bc16x2(v[6]) + bc16x2(v[7]);
        s0 = s0 + s1; s2 = s2 + s3; s0 = s0 + s2;
        accx += (float)s0[0]; accy += (float)s0[1];
    }
    if (j < end) {   // exactly 4 remain
        u32 v0 = hp[(size_t)col[j] * 64];
        u32 v1 = hp[(size_t)col[j + 1] * 64];
        u32 v2 = hp[(size_t)col[j + 2] * 64];
        u32 v3 = hp[(size_t)col[j + 3] * 64];
        f16x2 t0 = bc16x2(v0) + bc16x2(v1);
        f16x2 t1 = bc16x2(v2) + bc16x2(v3);
        t0 = t0 + t1;
        accx += (float)t0[0]; accy += (float)t0[1];
    }
    z[(size_t)node * 64 + c] = f22h(accx, accy);
}

// ---------------- fused MLP + LayerNorm + ReLU ----------------
// 512 threads = 8 waves; M-tile = 128 rows; wave w owns rows w*16..w*16+15.
// LDS: [0,32768) W1 image -> (after GEMM1) hidden buffer; [32768,65536) W2 image.
// Both W staged once up front; 2 barriers total.

__device__ __forceinline__ void stage_img64(const u32* __restrict__ img,
                                            unsigned char* lds, int tid) {
    #pragma unroll
    for (int i = 0; i < 8; ++i) {
        int b = tid * 16 + i * 8192;
        *(uint4*)(lds + b) = *(const uint4*)((const unsigned char*)img + b);
    }
}

__global__ __launch_bounds__(512, 4) void mlp_kernel(
    const u16* __restrict__ z16, const u32* __restrict__ imgpair,
    const float* __restrict__ b1v, const float* __restrict__ b2v,
    const float* __restrict__ gam, const float* __restrict__ bet,
    u16* __restrict__ h16out, float* __restrict__ f32out)
{
    __shared__ __align__(16) unsigned char lds[65536];
    const int tid = threadIdx.x;
    const int lane = tid & 63;
    const int w = tid >> 6;       // wave 0..7
    const int rl = lane & 15;
    const int kg = lane >> 4;
    const int tile = blockIdx.x * 128;
    const int r0 = tile + w * 16;

    stage_img64(imgpair, lds, tid);   // [W1 32K][W2 32K]

    int zrow = r0 + rl; if (zrow > NN - 1) zrow = NN - 1;
    const u16* zp = z16 + (size_t)zrow * 128;
    f16x8 afr[4];
    #pragma unroll
    for (int kt = 0; kt < 4; ++kt)
        afr[kt] = *(const f16x8*)(zp + kt * 32 + kg * 8);
    __syncthreads();   // barrier 1: W1+W2 staged

    // ---- GEMM1 fully into registers (all W1 reads complete before overwrite)
    f32x4 acc1[8];
    #pragma unroll
    for (int nt = 0; nt < 8; ++nt) {
        f32x4 acc = {0.f, 0.f, 0.f, 0.f};
        int c = nt * 16 + rl;
        #pragma unroll
        for (int kt = 0; kt < 4; ++kt) {
            int kb = kt * 32 + kg * 8;
            u32 off = ((((u32)c << 7) + kb) << 1) ^ (((u32)c & 7) << 4);
            f16x8 b = *(const f16x8*)(lds + off);
            acc = __builtin_amdgcn_mfma_f32_16x16x32_f16(afr[kt], b, acc, 0, 0, 0);
        }
        acc1[nt] = acc;
    }

    __syncthreads();   // barrier 2: every wave done reading W1

    // ---- bias + ReLU -> hidden buffer in W1's region (wave-private rows)
    #pragma unroll
    for (int nt = 0; nt < 8; ++nt) {
        int c = nt * 16 + rl;
        float bias = b1v[c];
        #pragma unroll
        for (int r = 0; r < 4; ++r) {
            float v = acc1[nt][r] + bias;
            v = v > 0.f ? v : 0.f;
            int fullrow = w * 16 + kg * 4 + r;     // 0..127
            u32 hoff = (((((u32)fullrow << 7) + c) << 1) ^ (((u32)fullrow & 7) << 4));
            *(u16*)(lds + hoff) = f2h_bits(v);
        }
    }

    // A-frags for GEMM2 from own rows (same-wave RAW; lgkmcnt only, no barrier)
    f16x8 afr2[4];
    int hrow = w * 16 + rl;
    #pragma unroll
    for (int kt = 0; kt < 4; ++kt) {
        int kb = kt * 32 + kg * 8;
        u32 off = (((((u32)hrow << 7) + kb) << 1) ^ (((u32)hrow & 7) << 4));
        afr2[kt] = *(const f16x8*)(lds + off);
    }

    // ---- GEMM2 + bias (W2 image at +32768)
    f32x4 acc2[8];
    #pragma unroll
    for (int nt = 0; nt < 8; ++nt) {
        f32x4 acc = {0.f, 0.f, 0.f, 0.f};
        int c = nt * 16 + rl;
        #pragma unroll
        for (int kt = 0; kt < 4; ++kt) {
            int kb = kt * 32 + kg * 8;
            u32 off = 32768u + (((((u32)c << 7) + kb) << 1) ^ (((u32)c & 7) << 4));
            f16x8 b = *(const f16x8*)(lds + off);
            acc = __builtin_amdgcn_mfma_f32_16x16x32_f16(afr2[kt], b, acc, 0, 0, 0);
        }
        float bias = b2v[c];
        acc[0] += bias; acc[1] += bias; acc[2] += bias; acc[3] += bias;
        acc2[nt] = acc;
    }

    // ---- LayerNorm + ReLU + store
    float gamv[8], betv[8];
    #pragma unroll
    for (int nt = 0; nt < 8; ++nt) { gamv[nt] = gam[nt * 16 + rl]; betv[nt] = bet[nt * 16 + rl]; }
    #pragma unroll
    for (int r = 0; r < 4; ++r) {
        float s1 = 0.f, s2 = 0.f;
        #pragma unroll
        for (int nt = 0; nt < 8; ++nt) { float v = acc2[nt][r]; s1 += v; s2 += v * v; }
        #pragma unroll
        for (int m = 1; m < 16; m <<= 1) {
            s1 += __shfl_xor(s1, m, 64);
            s2 += __shfl_xor(s2, m, 64);
        }
        float mu = s1 * (1.f / 128.f);
        float var = s2 * (1.f / 128.f) - mu * mu;
        float rstd = rsqrtf(var + 1e-5f);
        int fullrow = r0 + kg * 4 + r;
        if (fullrow < NN) {
            #pragma unroll
            for (int nt = 0; nt < 8; ++nt) {
                float v = (acc2[nt][r] - mu) * rstd * gamv[nt] + betv[nt];
                v = v > 0.f ? v : 0.f;
                if (h16out) h16out[(size_t)fullrow * 128 + nt * 16 + rl] = f2h_bits(v);
                if (f32out) f32out[(size_t)fullrow * 128 + nt * 16 + rl] = v;
            }
        }
    }
}

// ---------------- host ----------------

extern "C" void kernel_launch(void* const* d_in, const int* in_sizes, int n_in,
                              void* d_out, int out_size, void* d_ws, size_t ws_size,
                              hipStream_t stream) {
    const float* x     = (const float*)d_in[0];
    const int*   ei    = (const int*)d_in[1];
    const float* W1    = (const float*)d_in[2];
    const float* b1    = (const float*)d_in[3];
    const float* W2    = (const float*)d_in[4];
    const float* b2    = (const float*)d_in[5];
    const float* gamma = (const float*)d_in[6];
    const float* beta  = (const float*)d_in[7];
    float* out = (float*)d_out;

    const int* src = ei;
    const int* dst = ei + EE;

    unsigned char* ws = (unsigned char*)d_ws;
    size_t off = 0;
    int* hist_g  = (int*)(ws + off); off += (size_t)NBUCK * NCHUNK * 4;
    int* btot    = (int*)(ws + off); off += (size_t)(NBUCK + 1) * 4;
    int* bbase   = (int*)(ws + off); off += (size_t)(NBUCK + 1) * 4;
    int* rbeg    = (int*)(ws + off); off += (size_t)NN * 4;
    int* rpend   = (int*)(ws + off); off += (size_t)NN * 4; off = (off + 255) & ~(size_t)255;
    u16* wimg    = (u16*)(ws + off); off += (size_t)6 * 16384 * 2; off = (off + 255) & ~(size_t)255;
    u32* rec     = (u32*)(ws + off); off += (size_t)EE * 4; off = (off + 255) & ~(size_t)255;
    int* colv    = (int*)(ws + off); off += ((size_t)EE + (size_t)NBUCK * PADMAX + 64) * 4;
    off = (off + 255) & ~(size_t)255;
    u32* h16a    = (u32*)(ws + off); off += (size_t)(NN + 1) * 64 * 4;
    u32* h16b    = (u32*)(ws + off); off += (size_t)(NN + 1) * 64 * 4;
    u32* z16     = (u32*)(ws + off); off += (size_t)NN * 64 * 4;

    csr_hist<<<NCHUNK, 1024, 0, stream>>>(dst, hist_g);
    csr_scanA<<<NBUCK, 128, 0, stream>>>(hist_g, btot);
    csr_scanB<<<1, 512, 0, stream>>>(btot, bbase);
    csr_scatter<<<NCHUNK, 1024, 0, stream>>>(src, dst, hist_g, bbase, rec);
    csr_finalize<<<NBUCK, 256, 0, stream>>>(rec, bbase, rbeg, rpend, colv);
    wconv_kernel<<<48, 256, 0, stream>>>(W1, W2, wimg);
    cvt_kernel<<<NN * 32 / 256 + 1, 256, 0, stream>>>(x, h16a, h16b);

    const u32* hin = h16a;
    u32* hnext = h16b;
    for (int l = 0; l < LL; ++l) {
        agg16_kernel<<<NN / 4, 256, 0, stream>>>(hin, rbeg, rpend, colv, z16);
        mlp_kernel<<<(NN + 127) / 128, 512, 0, stream>>>(
            (const u16*)z16,
            (const u32*)(wimg + (size_t)(2 * l) * 16384),   // [W1|W2] contiguous 64KB
            b1 + l * DD, b2 + l * DD,
            gamma + l * DD, beta + l * DD,
            (l < LL - 1) ? (u16*)hnext : (u16*)nullptr,
            (l == LL - 1) ? out : (float*)nullptr);
        hin = hnext;
        hnext = (hnext == h16a) ? h16b : h16a;
    }
}

// Round 11
// 296.614 us; speedup vs baseline: 2.7322x; 1.0443x over previous
//
#include <hip/hip_runtime.h>

#define NN 100000
#define EE 1600000
#define DD 128
#define LL 3

typedef float f32x4 __attribute__((ext_vector_type(4)));
typedef _Float16 f16x8 __attribute__((ext_vector_type(8)));
typedef _Float16 f16x2 __attribute__((ext_vector_type(2)));
typedef unsigned short u16;
typedef unsigned int u32;
typedef u16 u16x8 __attribute__((ext_vector_type(8)));

// CSR-build geometry: buckets of 256 nodes, chunks of 16384 edges
#define NBUCK ((NN + 255) / 256)          // 391
#define CHUNK 16384
#define NCHUNK ((EE + CHUNK - 1) / CHUNK) // 98
#define PADMAX 768                         // 256 nodes * 3 max pad (mult-4)

#define WCONV_BLKS 12                      // 12288 threads / 1024
#define CVT_BLKS   3126                    // (NN*32 + 64 + 1023) / 1024

__device__ __forceinline__ u16 f2h_bits(float f) {
    _Float16 h = (_Float16)f;
    return __builtin_bit_cast(u16, h);
}
__device__ __forceinline__ f16x2 bc16x2(u32 v) {
    return __builtin_bit_cast(f16x2, v);
}
__device__ __forceinline__ u32 f22h(float x, float y) {
    return (u32)f2h_bits(x) | ((u32)f2h_bits(y) << 16);
}

// ---------------- fused prologue: [csr_hist | wconv | cvt] (independent work) ----------------

__global__ __launch_bounds__(1024) void prologue_kernel(
    const int* __restrict__ dst, int* __restrict__ hist_g,
    const float* __restrict__ W1, const float* __restrict__ W2, u16* __restrict__ img,
    const float* __restrict__ x, u32* __restrict__ ha, u32* __restrict__ hb) {
    __shared__ int h[NBUCK];
    int b = blockIdx.x, t = threadIdx.x;
    if (b < NCHUNK) {
        // ---- csr_hist: per-chunk histogram over buckets (bucket = dst >> 8)
        for (int i = t; i < NBUCK; i += 1024) h[i] = 0;
        __syncthreads();
        int base = b * CHUNK;
        #pragma unroll
        for (int i = 0; i < CHUNK / 1024; ++i) {
            int e = base + t + i * 1024;
            if (e < EE) atomicAdd(&h[dst[e] >> 8], 1);
        }
        __syncthreads();
        for (int i = t; i < NBUCK; i += 1024) hist_g[i * NCHUNK + b] = h[i];
    } else if (b < NCHUNK + WCONV_BLKS) {
        // ---- wconv: W (fp32) -> pre-swizzled fp16 images; 6 images of 2048 chunks
        int tt = (b - NCHUNK) * 1024 + t;
        if (tt < 6 * 2048) {
            int m = tt >> 11;
            int q = tt & 2047;
            int l = m >> 1;
            const float* W = ((m & 1) ? W2 : W1) + (size_t)l * DD * DD;
            int c = q & 127;
            int k0 = (q >> 7) << 3;
            u16x8 tv;
            #pragma unroll
            for (int j = 0; j < 8; ++j) tv[j] = f2h_bits(W[(k0 + j) * 128 + c]);
            u32 off = ((((u32)c << 7) + k0) << 1) ^ (((u32)c & 7) << 4);
            *(u16x8*)((unsigned char*)img + (size_t)m * 32768 + off) = tv;
        }
    } else {
        // ---- cvt: x (fp32) -> h16, plus zero row NN of both h buffers
        int i = (b - NCHUNK - WCONV_BLKS) * 1024 + t;
        if (i < NN * 32) {
            float4 v = ((const float4*)x)[i];
            ha[i * 2]     = f22h(v.x, v.y);
            ha[i * 2 + 1] = f22h(v.z, v.w);
        } else {
            int k = i - NN * 32;
            if (k < 64) {
                ha[(size_t)NN * 64 + k] = 0;
                hb[(size_t)NN * 64 + k] = 0;
            }
        }
    }
}

// ---------------- CSR build (rest) ----------------

// per-bucket exclusive scan of its chunk counts (in place) + bucket total
__global__ __launch_bounds__(128) void csr_scanA(int* __restrict__ hist_g,
                                                 int* __restrict__ btot) {
    __shared__ int sh[128];
    int b = blockIdx.x, t = threadIdx.x;
    int v = (t < NCHUNK) ? hist_g[b * NCHUNK + t] : 0;
    sh[t] = v; __syncthreads();
    for (int off = 1; off < 128; off <<= 1) {
        int u = (t >= off) ? sh[t - off] : 0;
        __syncthreads();
        sh[t] += u;
        __syncthreads();
    }
    if (t < NCHUNK) hist_g[b * NCHUNK + t] = sh[t] - v;
    if (t == 127) btot[b] = sh[127];
}

// single small block: exclusive scan of bucket totals
__global__ __launch_bounds__(512) void csr_scanB(const int* __restrict__ btot,
                                                 int* __restrict__ bbase) {
    __shared__ int sh[512];
    int t = threadIdx.x;
    int v = (t < NBUCK) ? btot[t] : 0;
    sh[t] = v; __syncthreads();
    for (int off = 1; off < 512; off <<= 1) {
        int u = (t >= off) ? sh[t - off] : 0;
        __syncthreads();
        sh[t] += u;
        __syncthreads();
    }
    if (t < NBUCK) bbase[t] = sh[t] - v;
    if (t == 0) bbase[NBUCK] = EE;
}

__global__ __launch_bounds__(1024) void csr_scatter(const int* __restrict__ src,
                                                    const int* __restrict__ dst,
                                                    const int* __restrict__ hist_g,
                                                    const int* __restrict__ bbase,
                                                    u32* __restrict__ rec) {
    __shared__ int cur[NBUCK];
    int t = threadIdx.x, c = blockIdx.x;
    for (int i = t; i < NBUCK; i += 1024) cur[i] = bbase[i] + hist_g[i * NCHUNK + c];
    __syncthreads();
    int base = c * CHUNK;
    #pragma unroll
    for (int i = 0; i < CHUNK / 1024; ++i) {
        int e = base + t + i * 1024;
        if (e < EE) {
            int d = dst[e];
            int slot = atomicAdd(&cur[d >> 8], 1);
            rec[slot] = (u32)src[e] | ((u32)(d & 255) << 17);
        }
    }
}

// one block per bucket: padded (multiple-of-4) per-node segments, pad -> node NN
__global__ __launch_bounds__(256) void csr_finalize(const u32* __restrict__ rec,
                                                    const int* __restrict__ bbase,
                                                    int* __restrict__ rbeg,
                                                    int* __restrict__ rpend,
                                                    int* __restrict__ col) {
    __shared__ int cur[256];
    __shared__ int sc[256];
    int b = blockIdx.x, t = threadIdx.x;
    int base = bbase[b], tot = bbase[b + 1] - base;
    int pbase = base + b * PADMAX;
    sc[t] = 0; __syncthreads();
    for (int r = t; r < tot; r += 256) atomicAdd(&sc[rec[base + r] >> 17], 1);
    __syncthreads();
    int cnt = sc[t];
    int pcnt = (cnt + 3) & ~3;
    sc[t] = pcnt; __syncthreads();
    for (int off = 1; off < 256; off <<= 1) {
        int u = (t >= off) ? sc[t - off] : 0;
        __syncthreads();
        sc[t] += u;
        __syncthreads();
    }
    int mybeg = pbase + sc[t] - pcnt;
    cur[t] = mybeg;
    int nid = b * 256 + t;
    if (nid < NN) { rbeg[nid] = mybeg; rpend[nid] = mybeg + pcnt; }
    for (int k = cnt; k < pcnt; ++k) col[mybeg + k] = NN;   // pad -> zero row
    __syncthreads();
    for (int r = t; r < tot; r += 256) {
        u32 rc = rec[base + r];
        int slot = atomicAdd(&cur[rc >> 17], 1);
        col[slot] = (int)(rc & 0x1FFFFu);
    }
}

// ---------------- aggregation: z16 = h16 + sum_{j in N(i)} h16[j] ----------------
// one wave per node; lane c holds halves [2c,2c+1]; lists padded to mult-4.
// 16 gathers in flight (main), then 8, then 4. Wave-uniform list bounds via
// readfirstlane so col[] reads compile to scalar loads (frees VMEM queue).

__global__ __launch_bounds__(256) void agg16_kernel(
    const u32* __restrict__ h, const int* __restrict__ rbeg,
    const int* __restrict__ rpend, const int* __restrict__ col,
    u32* __restrict__ z) {
    int node = blockIdx.x * 4 + (threadIdx.x >> 6);
    int c = threadIdx.x & 63;
    const u32* hp = h + c;
    f16x2 self = bc16x2(hp[(size_t)node * 64]);
    float accx = (float)self[0], accy = (float)self[1];
    int beg = __builtin_amdgcn_readfirstlane(rbeg[node]);
    int end = __builtin_amdgcn_readfirstlane(rpend[node]);
    int j = beg;
    for (; j + 16 <= end; j += 16) {
        u32 v[16];
        #pragma unroll
        for (int q = 0; q < 16; ++q) v[q] = hp[(size_t)col[j + q] * 64];
        // two 8-trees, fp32 master add after each (bit-identical to 2x 8-loop)
        f16x2 s0 = bc16x2(v[0]) + bc16x2(v[1]);
        f16x2 s1 = bc16x2(v[2]) + bc16x2(v[3]);
        f16x2 s2 = bc16x2(v[4]) + bc16x2(v[5]);
        f16x2 s3 = bc16x2(v[6]) + bc16x2(v[7]);
        s0 = s0 + s1; s2 = s2 + s3; s0 = s0 + s2;
        accx += (float)s0[0]; accy += (float)s0[1];
        f16x2 s4 = bc16x2(v[8]) + bc16x2(v[9]);
        f16x2 s5 = bc16x2(v[10]) + bc16x2(v[11]);
        f16x2 s6 = bc16x2(v[12]) + bc16x2(v[13]);
        f16x2 s7 = bc16x2(v[14]) + bc16x2(v[15]);
        s4 = s4 + s5; s6 = s6 + s7; s4 = s4 + s6;
        accx += (float)s4[0]; accy += (float)s4[1];
    }
    if (j + 8 <= end) {
        u32 v[8];
        #pragma unroll
        for (int q = 0; q < 8; ++q) v[q] = hp[(size_t)col[j + q] * 64];
        f16x2 s0 = bc16x2(v[0]) + bc16x2(v[1]);
        f16x2 s1 = bc16x2(v[2]) + bc16x2(v[3]);
        f16x2 s2 = bc16x2(v[4]) + bc16x2(v[5]);
        f16x2 s3 = bc16x2(v[6]) + bc16x2(v[7]);
        s0 = s0 + s1; s2 = s2 + s3; s0 = s0 + s2;
        accx += (float)s0[0]; accy += (float)s0[1];
        j += 8;
    }
    if (j < end) {   // exactly 4 remain
        u32 v0 = hp[(size_t)col[j] * 64];
        u32 v1 = hp[(size_t)col[j + 1] * 64];
        u32 v2 = hp[(size_t)col[j + 2] * 64];
        u32 v3 = hp[(size_t)col[j + 3] * 64];
        f16x2 t0 = bc16x2(v0) + bc16x2(v1);
        f16x2 t1 = bc16x2(v2) + bc16x2(v3);
        t0 = t0 + t1;
        accx += (float)t0[0]; accy += (float)t0[1];
    }
    z[(size_t)node * 64 + c] = f22h(accx, accy);
}

// ---------------- fused MLP + LayerNorm + ReLU ----------------
// 512 threads = 8 waves; M-tile = 128 rows; wave w owns rows w*16..w*16+15.
// LDS: [0,32768) W1 image -> (after GEMM1) hidden buffer; [32768,65536) W2 image.

__device__ __forceinline__ void stage_img64(const u32* __restrict__ img,
                                            unsigned char* lds, int tid) {
    #pragma unroll
    for (int i = 0; i < 8; ++i) {
        int b = tid * 16 + i * 8192;
        *(uint4*)(lds + b) = *(const uint4*)((const unsigned char*)img + b);
    }
}

__global__ __launch_bounds__(512, 4) void mlp_kernel(
    const u16* __restrict__ z16, const u32* __restrict__ imgpair,
    const float* __restrict__ b1v, const float* __restrict__ b2v,
    const float* __restrict__ gam, const float* __restrict__ bet,
    u16* __restrict__ h16out, float* __restrict__ f32out)
{
    __shared__ __align__(16) unsigned char lds[65536];
    const int tid = threadIdx.x;
    const int lane = tid & 63;
    const int w = tid >> 6;       // wave 0..7
    const int rl = lane & 15;
    const int kg = lane >> 4;
    const int tile = blockIdx.x * 128;
    const int r0 = tile + w * 16;

    stage_img64(imgpair, lds, tid);   // [W1 32K][W2 32K]

    int zrow = r0 + rl; if (zrow > NN - 1) zrow = NN - 1;
    const u16* zp = z16 + (size_t)zrow * 128;
    f16x8 afr[4];
    #pragma unroll
    for (int kt = 0; kt < 4; ++kt)
        afr[kt] = *(const f16x8*)(zp + kt * 32 + kg * 8);
    __syncthreads();   // barrier 1: W1+W2 staged

    // ---- GEMM1 fully into registers
    f32x4 acc1[8];
    #pragma unroll
    for (int nt = 0; nt < 8; ++nt) {
        f32x4 acc = {0.f, 0.f, 0.f, 0.f};
        int c = nt * 16 + rl;
        #pragma unroll
        for (int kt = 0; kt < 4; ++kt) {
            int kb = kt * 32 + kg * 8;
            u32 off = ((((u32)c << 7) + kb) << 1) ^ (((u32)c & 7) << 4);
            f16x8 b = *(const f16x8*)(lds + off);
            acc = __builtin_amdgcn_mfma_f32_16x16x32_f16(afr[kt], b, acc, 0, 0, 0);
        }
        acc1[nt] = acc;
    }

    __syncthreads();   // barrier 2: every wave done reading W1

    // ---- bias + ReLU -> hidden buffer in W1's region (wave-private rows)
    #pragma unroll
    for (int nt = 0; nt < 8; ++nt) {
        int c = nt * 16 + rl;
        float bias = b1v[c];
        #pragma unroll
        for (int r = 0; r < 4; ++r) {
            float v = acc1[nt][r] + bias;
            v = v > 0.f ? v : 0.f;
            int fullrow = w * 16 + kg * 4 + r;     // 0..127
            u32 hoff = (((((u32)fullrow << 7) + c) << 1) ^ (((u32)fullrow & 7) << 4));
            *(u16*)(lds + hoff) = f2h_bits(v);
        }
    }

    // A-frags for GEMM2 from own rows (same-wave RAW; lgkmcnt only)
    f16x8 afr2[4];
    int hrow = w * 16 + rl;
    #pragma unroll
    for (int kt = 0; kt < 4; ++kt) {
        int kb = kt * 32 + kg * 8;
        u32 off = (((((u32)hrow << 7) + kb) << 1) ^ (((u32)hrow & 7) << 4));
        afr2[kt] = *(const f16x8*)(lds + off);
    }

    // ---- GEMM2 + bias (W2 image at +32768)
    f32x4 acc2[8];
    #pragma unroll
    for (int nt = 0; nt < 8; ++nt) {
        f32x4 acc = {0.f, 0.f, 0.f, 0.f};
        int c = nt * 16 + rl;
        #pragma unroll
        for (int kt = 0; kt < 4; ++kt) {
            int kb = kt * 32 + kg * 8;
            u32 off = 32768u + (((((u32)c << 7) + kb) << 1) ^ (((u32)c & 7) << 4));
            f16x8 b = *(const f16x8*)(lds + off);
            acc = __builtin_amdgcn_mfma_f32_16x16x32_f16(afr2[kt], b, acc, 0, 0, 0);
        }
        float bias = b2v[c];
        acc[0] += bias; acc[1] += bias; acc[2] += bias; acc[3] += bias;
        acc2[nt] = acc;
    }

    // ---- LayerNorm + ReLU + store
    float gamv[8], betv[8];
    #pragma unroll
    for (int nt = 0; nt < 8; ++nt) { gamv[nt] = gam[nt * 16 + rl]; betv[nt] = bet[nt * 16 + rl]; }
    #pragma unroll
    for (int r = 0; r < 4; ++r) {
        float s1 = 0.f, s2 = 0.f;
        #pragma unroll
        for (int nt = 0; nt < 8; ++nt) { float v = acc2[nt][r]; s1 += v; s2 += v * v; }
        #pragma unroll
        for (int m = 1; m < 16; m <<= 1) {
            s1 += __shfl_xor(s1, m, 64);
            s2 += __shfl_xor(s2, m, 64);
        }
        float mu = s1 * (1.f / 128.f);
        float var = s2 * (1.f / 128.f) - mu * mu;
        float rstd = rsqrtf(var + 1e-5f);
        int fullrow = r0 + kg * 4 + r;
        if (fullrow < NN) {
            #pragma unroll
            for (int nt = 0; nt < 8; ++nt) {
                float v = (acc2[nt][r] - mu) * rstd * gamv[nt] + betv[nt];
                v = v > 0.f ? v : 0.f;
                if (h16out) h16out[(size_t)fullrow * 128 + nt * 16 + rl] = f2h_bits(v);
                if (f32out) f32out[(size_t)fullrow * 128 + nt * 16 + rl] = v;
            }
        }
    }
}

// ---------------- host ----------------

extern "C" void kernel_launch(void* const* d_in, const int* in_sizes, int n_in,
                              void* d_out, int out_size, void* d_ws, size_t ws_size,
                              hipStream_t stream) {
    const float* x     = (const float*)d_in[0];
    const int*   ei    = (const int*)d_in[1];
    const float* W1    = (const float*)d_in[2];
    const float* b1    = (const float*)d_in[3];
    const float* W2    = (const float*)d_in[4];
    const float* b2    = (const float*)d_in[5];
    const float* gamma = (const float*)d_in[6];
    const float* beta  = (const float*)d_in[7];
    float* out = (float*)d_out;

    const int* src = ei;
    const int* dst = ei + EE;

    unsigned char* ws = (unsigned char*)d_ws;
    size_t off = 0;
    int* hist_g  = (int*)(ws + off); off += (size_t)NBUCK * NCHUNK * 4;
    int* btot    = (int*)(ws + off); off += (size_t)(NBUCK + 1) * 4;
    int* bbase   = (int*)(ws + off); off += (size_t)(NBUCK + 1) * 4;
    int* rbeg    = (int*)(ws + off); off += (size_t)NN * 4;
    int* rpend   = (int*)(ws + off); off += (size_t)NN * 4; off = (off + 255) & ~(size_t)255;
    u16* wimg    = (u16*)(ws + off); off += (size_t)6 * 16384 * 2; off = (off + 255) & ~(size_t)255;
    u32* rec     = (u32*)(ws + off); off += (size_t)EE * 4; off = (off + 255) & ~(size_t)255;
    int* colv    = (int*)(ws + off); off += ((size_t)EE + (size_t)NBUCK * PADMAX + 64) * 4;
    off = (off + 255) & ~(size_t)255;
    u32* h16a    = (u32*)(ws + off); off += (size_t)(NN + 1) * 64 * 4;
    u32* h16b    = (u32*)(ws + off); off += (size_t)(NN + 1) * 64 * 4;
    u32* z16     = (u32*)(ws + off); off += (size_t)NN * 64 * 4;

    prologue_kernel<<<NCHUNK + WCONV_BLKS + CVT_BLKS, 1024, 0, stream>>>(
        dst, hist_g, W1, W2, wimg, x, h16a, h16b);
    csr_scanA<<<NBUCK, 128, 0, stream>>>(hist_g, btot);
    csr_scanB<<<1, 512, 0, stream>>>(btot, bbase);
    csr_scatter<<<NCHUNK, 1024, 0, stream>>>(src, dst, hist_g, bbase, rec);
    csr_finalize<<<NBUCK, 256, 0, stream>>>(rec, bbase, rbeg, rpend, colv);

    const u32* hin = h16a;
    u32* hnext = h16b;
    for (int l = 0; l < LL; ++l) {
        agg16_kernel<<<NN / 4, 256, 0, stream>>>(hin, rbeg, rpend, colv, z16);
        mlp_kernel<<<(NN + 127) / 128, 512, 0, stream>>>(
            (const u16*)z16,
            (const u32*)(wimg + (size_t)(2 * l) * 16384),   // [W1|W2] contiguous 64KB
            b1 + l * DD, b2 + l * DD,
            gamma + l * DD, beta + l * DD,
            (l < LL - 1) ? (u16*)hnext : (u16*)nullptr,
            (l == LL - 1) ? out : (float*)nullptr);
        hin = hnext;
        hnext = (hnext == h16a) ? h16b : h16a;
    }
}